// Round 3
// baseline (949.891 us; speedup 1.0000x reference)
//
#include <hip/hip_runtime.h>

// ---------------------------------------------------------------------------
// GNN: 3x GraphConv (norm='both') + avg-pool + MLP(128->512->256->1), fp32.
// R3: 8-way XCD-local replicas (blockIdx&7 ~ XCD id under round-robin
// dispatch) for degree histograms AND CSR cursors -> atomics stay in one
// XCD's L2, no cross-XCD line bouncing. Correct for ANY dispatch mapping
// (hist & fill compute the same replica per edge from blockIdx).
// ---------------------------------------------------------------------------

static inline int ceil_div(int a, int b){ return (a + b - 1) / b; }

// 8-replica histogram: replica = blockIdx & 7 (must match fill_csr8's mapping!)
__global__ void hist8_kernel(const int* __restrict__ src, const int* __restrict__ dst,
                             unsigned* __restrict__ d8out, unsigned* __restrict__ d8in,
                             int E, int N){
  int e = blockIdx.x*blockDim.x + threadIdx.x;
  int r = blockIdx.x & 7;
  if (e < E){
    atomicAdd(&d8out[(size_t)r*N + src[e]], 1u);
    atomicAdd(&d8in [(size_t)r*N + dst[e]], 1u);
  }
}

__global__ void inv8_kernel(const unsigned* __restrict__ d8out, const unsigned* __restrict__ d8in,
                            float* __restrict__ inv_src, float* __restrict__ inv_dst,
                            unsigned* __restrict__ dintot, int N){
  int i = blockIdx.x*blockDim.x + threadIdx.x;
  if (i < N){
    unsigned a = 0, b = 0;
    #pragma unroll
    for (int r = 0; r < 8; r++){
      a += d8out[(size_t)r*N + i];
      b += d8in [(size_t)r*N + i];
    }
    dintot[i] = b;
    if (a < 1u) a = 1u;
    if (b < 1u) b = 1u;
    inv_src[i] = rsqrtf((float)a);
    inv_dst[i] = rsqrtf((float)b);
  }
}

// --- 3-kernel exclusive scan of in-degrees -> row_ptr ------------------------
__global__ void scan1_kernel(const unsigned* __restrict__ din, unsigned* __restrict__ excl,
                             unsigned* __restrict__ bsum, int N){
  __shared__ unsigned s[256];
  int t = threadIdx.x; int i = blockIdx.x*256 + t;
  unsigned x = (i < N) ? din[i] : 0u;
  s[t] = x; __syncthreads();
  for (int off = 1; off < 256; off <<= 1){
    unsigned v = (t >= off) ? s[t-off] : 0u;
    __syncthreads();
    s[t] += v;
    __syncthreads();
  }
  if (i < N) excl[i] = s[t] - x;
  if (t == 255) bsum[blockIdx.x] = s[255];
}

__global__ void scan2_kernel(unsigned* __restrict__ bsum, int nb){
  __shared__ unsigned s[1024];
  int t = threadIdx.x;
  unsigned x = (t < nb) ? bsum[t] : 0u;
  s[t] = x; __syncthreads();
  for (int off = 1; off < 1024; off <<= 1){
    unsigned v = (t >= off) ? s[t-off] : 0u;
    __syncthreads();
    s[t] += v;
    __syncthreads();
  }
  if (t < nb) bsum[t] = s[t] - x;
}

// row_ptr + per-replica cursor bases (disjoint slot segments per (replica,node))
__global__ void scan3_kernel(const unsigned* __restrict__ excl, const unsigned* __restrict__ bsum,
                             const unsigned* __restrict__ d8in,
                             int* __restrict__ row_ptr, int* __restrict__ cursor8, int N, int E){
  int i = blockIdx.x*blockDim.x + threadIdx.x;
  if (i < N){
    int v = (int)(excl[i] + bsum[i >> 8]);
    row_ptr[i] = v;
    int base = v;
    #pragma unroll
    for (int r = 0; r < 8; r++){
      cursor8[(size_t)r*N + i] = base;
      base += (int)d8in[(size_t)r*N + i];
    }
  }
  if (i == 0) row_ptr[N] = E;
}

__global__ void fill_csr8_kernel(const int* __restrict__ src, const int* __restrict__ dst,
                                 int* __restrict__ cursor8, int* __restrict__ col, int E, int N){
  int e = blockIdx.x*blockDim.x + threadIdx.x;
  int r = blockIdx.x & 7;
  if (e < E){
    int p = atomicAdd(&cursor8[(size_t)r*N + dst[e]], 1);
    col[p] = src[e];
  }
}

// hs = feats * inv_src (row scale), float4 vectorized
__global__ void scale_rows_kernel(const float* __restrict__ in, const float* __restrict__ sc,
                                  float* __restrict__ out, int n4){
  int i = blockIdx.x*blockDim.x + threadIdx.x;
  if (i < n4){
    float4 v = ((const float4*)in)[i];
    float s = sc[i >> 5];            // 32 float4 per 128-wide row
    v.x *= s; v.y *= s; v.z *= s; v.w *= s;
    ((float4*)out)[i] = v;
  }
}

// One wave per node; lane owns a float2 (128 floats = 64 lanes x 2), unroll x4.
__global__ __launch_bounds__(256) void csr_agg_kernel(
    const int* __restrict__ row_ptr, const int* __restrict__ col,
    const float* __restrict__ hs, float* __restrict__ agg, int N){
  int w = (int)((blockIdx.x*256u + threadIdx.x) >> 6);
  int lane = threadIdx.x & 63;
  if (w >= N) return;
  int r0 = __builtin_amdgcn_readfirstlane(row_ptr[w]);
  int r1 = __builtin_amdgcn_readfirstlane(row_ptr[w+1]);
  float ax0=0.f, ay0=0.f, ax1=0.f, ay1=0.f;
  float ax2=0.f, ay2=0.f, ax3=0.f, ay3=0.f;
  int e = r0;
  for (; e + 3 < r1; e += 4){
    int s0 = __builtin_amdgcn_readfirstlane(col[e]);
    int s1 = __builtin_amdgcn_readfirstlane(col[e+1]);
    int s2 = __builtin_amdgcn_readfirstlane(col[e+2]);
    int s3 = __builtin_amdgcn_readfirstlane(col[e+3]);
    float2 v0 = ((const float2*)(hs + (size_t)s0*128))[lane];
    float2 v1 = ((const float2*)(hs + (size_t)s1*128))[lane];
    float2 v2 = ((const float2*)(hs + (size_t)s2*128))[lane];
    float2 v3 = ((const float2*)(hs + (size_t)s3*128))[lane];
    ax0 += v0.x; ay0 += v0.y;
    ax1 += v1.x; ay1 += v1.y;
    ax2 += v2.x; ay2 += v2.y;
    ax3 += v3.x; ay3 += v3.y;
  }
  for (; e < r1; e++){
    int s0 = __builtin_amdgcn_readfirstlane(col[e]);
    float2 v0 = ((const float2*)(hs + (size_t)s0*128))[lane];
    ax0 += v0.x; ay0 += v0.y;
  }
  float2 r;
  r.x = (ax0 + ax1) + (ax2 + ax3);
  r.y = (ay0 + ay1) + (ay2 + ay3);
  ((float2*)(agg + (size_t)w*128))[lane] = r;
}

// Tiled fp32 SGEMM: out[M x Ncols] = act( (A .* row_scale) @ W + bias ) .* out_scale
// BM=64, BN=128, BK=32; 256 threads; 8x4 register tile per thread.
__global__ __launch_bounds__(256) void gemm_kernel(
    const float* __restrict__ A, const float* __restrict__ W,
    const float* __restrict__ bias, const float* __restrict__ row_scale,
    const float* __restrict__ out_scale, float* __restrict__ out,
    int M, int K, int Ncols, int do_relu){
  __shared__ float As[32][68];
  __shared__ float Bs[32][128];

  const int tid = threadIdx.x;
  const int tx = tid & 31;         // col group: 4 cols
  const int ty = tid >> 5;         // row group: 8 rows
  const int row0 = blockIdx.x * 64;
  const int col0 = blockIdx.y * 128;

  float acc[8][4];
  #pragma unroll
  for (int i = 0; i < 8; i++)
    #pragma unroll
    for (int j = 0; j < 4; j++) acc[i][j] = 0.f;

  for (int kb = 0; kb < K; kb += 32){
    #pragma unroll
    for (int i = 0; i < 2; i++){
      int flat = i*256 + tid;
      int m = flat >> 3, k4 = (flat & 7) << 2;
      int gm = row0 + m;
      float4 v = make_float4(0.f, 0.f, 0.f, 0.f);
      if (gm < M){
        v = *(const float4*)(A + (size_t)gm*K + kb + k4);
        if (row_scale){ float s = row_scale[gm]; v.x*=s; v.y*=s; v.z*=s; v.w*=s; }
      }
      As[k4+0][m] = v.x; As[k4+1][m] = v.y; As[k4+2][m] = v.z; As[k4+3][m] = v.w;
    }
    #pragma unroll
    for (int i = 0; i < 4; i++){
      int flat = i*256 + tid;
      int k = flat >> 5, j4 = (flat & 31) << 2;
      float4 v = *(const float4*)(W + (size_t)(kb + k)*Ncols + col0 + j4);
      *(float4*)&Bs[k][j4] = v;
    }
    __syncthreads();
    #pragma unroll
    for (int k = 0; k < 32; k++){
      float4 b = *(const float4*)&Bs[k][tx << 2];
      float a[8];
      #pragma unroll
      for (int i = 0; i < 8; i++) a[i] = As[k][ty*8 + i];
      #pragma unroll
      for (int i = 0; i < 8; i++){
        acc[i][0] = fmaf(a[i], b.x, acc[i][0]);
        acc[i][1] = fmaf(a[i], b.y, acc[i][1]);
        acc[i][2] = fmaf(a[i], b.z, acc[i][2]);
        acc[i][3] = fmaf(a[i], b.w, acc[i][3]);
      }
    }
    __syncthreads();
  }

  float4 bi = *(const float4*)(bias + col0 + (tx << 2));
  #pragma unroll
  for (int i = 0; i < 8; i++){
    int gm = row0 + ty*8 + i;
    if (gm < M){
      float4 v;
      v.x = acc[i][0] + bi.x; v.y = acc[i][1] + bi.y;
      v.z = acc[i][2] + bi.z; v.w = acc[i][3] + bi.w;
      if (do_relu){
        v.x = fmaxf(v.x, 0.f); v.y = fmaxf(v.y, 0.f);
        v.z = fmaxf(v.z, 0.f); v.w = fmaxf(v.w, 0.f);
      }
      if (out_scale){ float s = out_scale[gm]; v.x*=s; v.y*=s; v.z*=s; v.w*=s; }
      *(float4*)(out + (size_t)gm*Ncols + col0 + (tx << 2)) = v;
    }
  }
}

// Avg-pool per graph: graph_ids sorted -> binary search bounds, wave per graph.
__global__ void pool_kernel(const float* __restrict__ h, const int* __restrict__ gid,
                            float* __restrict__ emb, int N, int G){
  int g = blockIdx.x;
  int lane = threadIdx.x;   // 64 threads
  int lo = 0, hi = N;
  while (lo < hi){ int mid = (lo + hi) >> 1; if (gid[mid] < g) lo = mid + 1; else hi = mid; }
  int start = lo;
  hi = N;
  while (lo < hi){ int mid = (lo + hi) >> 1; if (gid[mid] <= g) lo = mid + 1; else hi = mid; }
  int end = lo;
  float ax = 0.f, ay = 0.f;
  for (int n = start; n < end; n++){
    float2 v = ((const float2*)(h + (size_t)n*128))[lane];
    ax += v.x; ay += v.y;
  }
  int c = end - start; if (c < 1) c = 1;
  float invc = 1.0f / (float)c;
  float2 r; r.x = ax * invc; r.y = ay * invc;
  ((float2*)(emb + (size_t)g*128))[lane] = r;
}

// Final 256->1: wave per graph, float4 per lane, shuffle reduce.
__global__ void final_dot_kernel(const float* __restrict__ x, const float* __restrict__ w,
                                 const float* __restrict__ b, float* __restrict__ out, int G){
  int idx = blockIdx.x*blockDim.x + threadIdx.x;
  int g = idx >> 6, lane = idx & 63;
  if (g >= G) return;
  float4 xv = ((const float4*)(x + (size_t)g*256))[lane];
  float4 wv = ((const float4*)w)[lane];
  float s = xv.x*wv.x + xv.y*wv.y + xv.z*wv.z + xv.w*wv.w;
  for (int off = 32; off > 0; off >>= 1) s += __shfl_down(s, off);
  if (lane == 0) out[g] = s + b[0];
}

extern "C" void kernel_launch(void* const* d_in, const int* in_sizes, int n_in,
                              void* d_out, int out_size, void* d_ws, size_t ws_size,
                              hipStream_t stream){
  const float* feats = (const float*)d_in[0];
  const int*   src   = (const int*)d_in[1];
  const int*   dst   = (const int*)d_in[2];
  const int*   gid   = (const int*)d_in[3];
  const float* W0 = (const float*)d_in[4];   const float* b0 = (const float*)d_in[5];
  const float* W1 = (const float*)d_in[6];   const float* b1 = (const float*)d_in[7];
  const float* W2 = (const float*)d_in[8];   const float* b2 = (const float*)d_in[9];
  const float* Wm0 = (const float*)d_in[10]; const float* bm0 = (const float*)d_in[11];
  const float* Wm1 = (const float*)d_in[12]; const float* bm1 = (const float*)d_in[13];
  const float* Wm2 = (const float*)d_in[14]; const float* bm2 = (const float*)d_in[15];
  float* out = (float*)d_out;

  const int E   = in_sizes[1];
  const int N   = in_sizes[3];
  const int G   = out_size;
  const int MH  = in_sizes[11];   // 512
  const int MH2 = in_sizes[13];   // 256

  char* ws = (char*)d_ws;
  size_t off = 0;
  auto carve = [&](size_t bytes) -> char* {
    off = (off + 255) & ~(size_t)255;
    char* p = ws + off; off += bytes; return p;
  };
  float* inv_src = (float*)carve((size_t)N*4);
  float* inv_dst = (float*)carve((size_t)N*4);
  int* row_ptr = (int*)carve((size_t)(N+1)*4);
  int* col     = (int*)carve((size_t)E*4);
  float* hs  = (float*)carve((size_t)N*128*4);
  float* agg = (float*)carve((size_t)N*128*4);
  float* emb = (float*)carve((size_t)G*128*4);
  float* x1  = (float*)carve((size_t)G*MH*4);
  float* x2  = (float*)carve((size_t)G*MH2*4);

  // CSR-build temporaries alias agg (dead until first csr_agg):
  // layout (u32 units): d8out[8N] | d8in[8N] | dintot[N] | excl[N] | bsum[4096] | cursor8[8N]
  unsigned* T = (unsigned*)agg;
  unsigned* d8out  = T;
  unsigned* d8in   = T + 8*(size_t)N;
  unsigned* dintot = T + 16*(size_t)N;
  unsigned* excl   = T + 17*(size_t)N;
  unsigned* bsum   = T + 18*(size_t)N;
  int*      cursor8= (int*)(T + 18*(size_t)N + 4096);

  hipMemsetAsync(d8out, 0, (size_t)16*N*4, stream);   // zeros d8out and d8in

  hist8_kernel<<<ceil_div(E,256), 256, 0, stream>>>(src, dst, d8out, d8in, E, N);
  inv8_kernel<<<ceil_div(N,256), 256, 0, stream>>>(d8out, d8in, inv_src, inv_dst, dintot, N);
  int nb = ceil_div(N, 256);
  scan1_kernel<<<nb, 256, 0, stream>>>(dintot, excl, bsum, N);
  scan2_kernel<<<1, 1024, 0, stream>>>(bsum, nb);
  scan3_kernel<<<nb, 256, 0, stream>>>(excl, bsum, d8in, row_ptr, cursor8, N, E);
  fill_csr8_kernel<<<ceil_div(E,256), 256, 0, stream>>>(src, dst, cursor8, col, E, N);
  scale_rows_kernel<<<ceil_div(N*32,256), 256, 0, stream>>>(feats, inv_src, hs, N*32);

  const int agg_blocks = ceil_div(N*64, 256);
  dim3 ggrid(ceil_div(N,64), 1);
  // layer 0: agg = CSR-sum(hs); hs = relu(agg*inv_dst @ W0 + b0) * inv_src
  csr_agg_kernel<<<agg_blocks, 256, 0, stream>>>(row_ptr, col, hs, agg, N);
  gemm_kernel<<<ggrid, 256, 0, stream>>>(agg, W0, b0, inv_dst, inv_src, hs, N, 128, 128, 1);
  // layer 1
  csr_agg_kernel<<<agg_blocks, 256, 0, stream>>>(row_ptr, col, hs, agg, N);
  gemm_kernel<<<ggrid, 256, 0, stream>>>(agg, W1, b1, inv_dst, inv_src, hs, N, 128, 128, 1);
  // layer 2 (no out_scale: plain h3 for pooling)
  csr_agg_kernel<<<agg_blocks, 256, 0, stream>>>(row_ptr, col, hs, agg, N);
  gemm_kernel<<<ggrid, 256, 0, stream>>>(agg, W2, b2, inv_dst, nullptr, hs, N, 128, 128, 1);
  // avg pooling
  pool_kernel<<<G, 64, 0, stream>>>(hs, gid, emb, N, G);
  // MLP head
  gemm_kernel<<<dim3(ceil_div(G,64), MH/128),  256, 0, stream>>>(emb, Wm0, bm0, nullptr, nullptr, x1, G, 128, MH, 1);
  gemm_kernel<<<dim3(ceil_div(G,64), MH2/128), 256, 0, stream>>>(x1, Wm1, bm1, nullptr, nullptr, x2, G, MH, MH2, 1);
  final_dot_kernel<<<ceil_div(G*64,256), 256, 0, stream>>>(x2, Wm2, bm2, out, G);
}

// Round 4
// 825.771 us; speedup vs baseline: 1.1503x; 1.1503x over previous
//
#include <hip/hip_runtime.h>

// ---------------------------------------------------------------------------
// GNN: 3x GraphConv (norm='both') + avg-pool + MLP(128->512->256->1), fp32.
// R4: atomic-free CSR build via two-pass LDS-privatized counting sort.
// R1-R3 showed random 4B global atomics/stores run at a hard ~26G trans/s
// (32-64B HBM sector per access) regardless of replication -> eliminate them.
// Buckets of 128 nodes (dst>>7); per-block LDS hist + reserved-offset scatter;
// per-bucket finalize does LDS hist/scan and writes col in a contiguous range.
// ---------------------------------------------------------------------------

static inline int ceil_div(int a, int b){ return (a + b - 1) / b; }

#define B1 128          // pass-1 blocks
#define NBMAX 1024      // max buckets (N <= 131072)

// Pass 1a: per-block bucket counts for dst (job A) and src (job B).
__global__ __launch_bounds__(256) void bucket_count_kernel(
    const int* __restrict__ src, const int* __restrict__ dst,
    unsigned* __restrict__ cntA, unsigned* __restrict__ cntB,
    int E, int NB){
  __shared__ unsigned la[NBMAX], lb[NBMAX];
  int t = threadIdx.x;
  for (int i = t; i < NB; i += 256){ la[i] = 0u; lb[i] = 0u; }
  __syncthreads();
  int chunk = (E + B1 - 1) / B1;
  int e0 = blockIdx.x * chunk, e1 = min(e0 + chunk, E);
  for (int e = e0 + t; e < e1; e += 256){
    atomicAdd(&la[dst[e] >> 7], 1u);
    atomicAdd(&lb[src[e] >> 7], 1u);
  }
  __syncthreads();
  for (int i = t; i < NB; i += 256){
    cntA[(size_t)blockIdx.x * NB + i] = la[i];
    cntB[(size_t)blockIdx.x * NB + i] = lb[i];
  }
}

// Column-wise exclusive scan over blocks for each bucket; emits totals.
// grid: (ceil(NB/256), 2): y=0 -> cntA, y=1 -> cntB.
__global__ void scan_cols_kernel(unsigned* __restrict__ cntA, unsigned* __restrict__ cntB,
                                 unsigned* __restrict__ totals, int NB){
  int b = blockIdx.x * 256 + threadIdx.x;
  if (b >= NB) return;
  unsigned* cnt = blockIdx.y ? cntB : cntA;
  unsigned run = 0;
  for (int blk = 0; blk < B1; blk++){
    unsigned v = cnt[(size_t)blk * NB + b];
    cnt[(size_t)blk * NB + b] = run;
    run += v;
  }
  totals[(size_t)blockIdx.y * NB + b] = run;
}

// Single-block exclusive scan of bucket totals -> baseA/baseB (each NB+1).
__global__ void scan_base_kernel(const unsigned* __restrict__ totals,
                                 unsigned* __restrict__ baseA, unsigned* __restrict__ baseB,
                                 int NB, int E){
  __shared__ unsigned s[NBMAX];
  int t = threadIdx.x;  // 1024 threads, NB <= 1024
  for (int job = 0; job < 2; job++){
    unsigned* base = job ? baseB : baseA;
    unsigned x = (t < NB) ? totals[(size_t)job * NB + t] : 0u;
    s[t] = x;
    __syncthreads();
    for (int off = 1; off < NBMAX; off <<= 1){
      unsigned v = (t >= off) ? s[t - off] : 0u;
      __syncthreads();
      s[t] += v;
      __syncthreads();
    }
    if (t < NB) base[t] = s[t] - x;
    if (t == 0) base[NB] = (unsigned)E;
    __syncthreads();
  }
}

// Pass 1b: scatter edges into bucketed arrays using per-block reserved offsets.
__global__ __launch_bounds__(256) void bucket_scatter_kernel(
    const int* __restrict__ src, const int* __restrict__ dst,
    const unsigned* __restrict__ cntA, const unsigned* __restrict__ cntB,
    const unsigned* __restrict__ baseA, const unsigned* __restrict__ baseB,
    int* __restrict__ bsrc_d, int* __restrict__ bdst_d, int* __restrict__ bsrc_s,
    int E, int NB){
  __shared__ unsigned curA[NBMAX], curB[NBMAX];
  int t = threadIdx.x;
  for (int i = t; i < NB; i += 256){
    curA[i] = baseA[i] + cntA[(size_t)blockIdx.x * NB + i];
    curB[i] = baseB[i] + cntB[(size_t)blockIdx.x * NB + i];
  }
  __syncthreads();
  int chunk = (E + B1 - 1) / B1;
  int e0 = blockIdx.x * chunk, e1 = min(e0 + chunk, E);
  for (int e = e0 + t; e < e1; e += 256){
    int s = src[e], d = dst[e];
    unsigned p = atomicAdd(&curA[d >> 7], 1u);
    bsrc_d[p] = s;
    bdst_d[p] = d;
    unsigned q = atomicAdd(&curB[s >> 7], 1u);
    bsrc_s[q] = s;
  }
}

// Pass 2a: per-bucket CSR finalize: row_ptr, inv_dst, col (contiguous range).
__global__ __launch_bounds__(256) void csr_finalize_kernel(
    const int* __restrict__ bsrc_d, const int* __restrict__ bdst_d,
    const unsigned* __restrict__ baseA,
    int* __restrict__ row_ptr, float* __restrict__ inv_dst, int* __restrict__ col,
    int N, int E, int NB){
  __shared__ unsigned cnt[128];
  __shared__ unsigned scn[128];
  int b = blockIdx.x, t = threadIdx.x;
  int node0 = b << 7;
  int nn = min(128, N - node0);
  int e0 = (int)baseA[b], e1 = (int)baseA[b + 1];
  if (t < 128) cnt[t] = 0u;
  __syncthreads();
  for (int e = e0 + t; e < e1; e += 256)
    atomicAdd(&cnt[bdst_d[e] & 127], 1u);
  __syncthreads();
  unsigned mycnt = (t < 128) ? cnt[t] : 0u;
  if (t < 128) scn[t] = mycnt;
  __syncthreads();
  for (int off = 1; off < 128; off <<= 1){
    unsigned v = (t < 128 && t >= off) ? scn[t - off] : 0u;
    __syncthreads();
    if (t < 128) scn[t] += v;
    __syncthreads();
  }
  if (t < nn){
    unsigned excl = scn[t] - mycnt;
    row_ptr[node0 + t] = e0 + (int)excl;
    unsigned c = mycnt < 1u ? 1u : mycnt;
    inv_dst[node0 + t] = rsqrtf((float)c);
    cnt[t] = (unsigned)e0 + excl;   // reuse as cursor
  }
  if (b == NB - 1 && t == 0) row_ptr[N] = E;
  __syncthreads();
  for (int e = e0 + t; e < e1; e += 256){
    unsigned p = atomicAdd(&cnt[bdst_d[e] & 127], 1u);
    col[p] = bsrc_d[e];
  }
}

// Pass 2b: per-bucket out-degree -> inv_src.
__global__ __launch_bounds__(256) void degout_finalize_kernel(
    const int* __restrict__ bsrc_s, const unsigned* __restrict__ baseB,
    float* __restrict__ inv_src, int N){
  __shared__ unsigned cnt[128];
  int b = blockIdx.x, t = threadIdx.x;
  int node0 = b << 7;
  int nn = min(128, N - node0);
  int e0 = (int)baseB[b], e1 = (int)baseB[b + 1];
  if (t < 128) cnt[t] = 0u;
  __syncthreads();
  for (int e = e0 + t; e < e1; e += 256)
    atomicAdd(&cnt[bsrc_s[e] & 127], 1u);
  __syncthreads();
  if (t < nn){
    unsigned c = cnt[t] < 1u ? 1u : cnt[t];
    inv_src[node0 + t] = rsqrtf((float)c);
  }
}

// hs = feats * inv_src (row scale), float4 vectorized
__global__ void scale_rows_kernel(const float* __restrict__ in, const float* __restrict__ sc,
                                  float* __restrict__ out, int n4){
  int i = blockIdx.x*blockDim.x + threadIdx.x;
  if (i < n4){
    float4 v = ((const float4*)in)[i];
    float s = sc[i >> 5];            // 32 float4 per 128-wide row
    v.x *= s; v.y *= s; v.z *= s; v.w *= s;
    ((float4*)out)[i] = v;
  }
}

// One wave per node; lane owns a float2 (128 floats = 64 lanes x 2), unroll x4.
__global__ __launch_bounds__(256) void csr_agg_kernel(
    const int* __restrict__ row_ptr, const int* __restrict__ col,
    const float* __restrict__ hs, float* __restrict__ agg, int N){
  int w = (int)((blockIdx.x*256u + threadIdx.x) >> 6);
  int lane = threadIdx.x & 63;
  if (w >= N) return;
  int r0 = __builtin_amdgcn_readfirstlane(row_ptr[w]);
  int r1 = __builtin_amdgcn_readfirstlane(row_ptr[w+1]);
  float ax0=0.f, ay0=0.f, ax1=0.f, ay1=0.f;
  float ax2=0.f, ay2=0.f, ax3=0.f, ay3=0.f;
  int e = r0;
  for (; e + 3 < r1; e += 4){
    int s0 = __builtin_amdgcn_readfirstlane(col[e]);
    int s1 = __builtin_amdgcn_readfirstlane(col[e+1]);
    int s2 = __builtin_amdgcn_readfirstlane(col[e+2]);
    int s3 = __builtin_amdgcn_readfirstlane(col[e+3]);
    float2 v0 = ((const float2*)(hs + (size_t)s0*128))[lane];
    float2 v1 = ((const float2*)(hs + (size_t)s1*128))[lane];
    float2 v2 = ((const float2*)(hs + (size_t)s2*128))[lane];
    float2 v3 = ((const float2*)(hs + (size_t)s3*128))[lane];
    ax0 += v0.x; ay0 += v0.y;
    ax1 += v1.x; ay1 += v1.y;
    ax2 += v2.x; ay2 += v2.y;
    ax3 += v3.x; ay3 += v3.y;
  }
  for (; e < r1; e++){
    int s0 = __builtin_amdgcn_readfirstlane(col[e]);
    float2 v0 = ((const float2*)(hs + (size_t)s0*128))[lane];
    ax0 += v0.x; ay0 += v0.y;
  }
  float2 r;
  r.x = (ax0 + ax1) + (ax2 + ax3);
  r.y = (ay0 + ay1) + (ay2 + ay3);
  ((float2*)(agg + (size_t)w*128))[lane] = r;
}

// Tiled fp32 SGEMM: out[M x Ncols] = act( (A .* row_scale) @ W + bias ) .* out_scale
__global__ __launch_bounds__(256) void gemm_kernel(
    const float* __restrict__ A, const float* __restrict__ W,
    const float* __restrict__ bias, const float* __restrict__ row_scale,
    const float* __restrict__ out_scale, float* __restrict__ out,
    int M, int K, int Ncols, int do_relu){
  __shared__ float As[32][68];
  __shared__ float Bs[32][128];

  const int tid = threadIdx.x;
  const int tx = tid & 31;
  const int ty = tid >> 5;
  const int row0 = blockIdx.x * 64;
  const int col0 = blockIdx.y * 128;

  float acc[8][4];
  #pragma unroll
  for (int i = 0; i < 8; i++)
    #pragma unroll
    for (int j = 0; j < 4; j++) acc[i][j] = 0.f;

  for (int kb = 0; kb < K; kb += 32){
    #pragma unroll
    for (int i = 0; i < 2; i++){
      int flat = i*256 + tid;
      int m = flat >> 3, k4 = (flat & 7) << 2;
      int gm = row0 + m;
      float4 v = make_float4(0.f, 0.f, 0.f, 0.f);
      if (gm < M){
        v = *(const float4*)(A + (size_t)gm*K + kb + k4);
        if (row_scale){ float s = row_scale[gm]; v.x*=s; v.y*=s; v.z*=s; v.w*=s; }
      }
      As[k4+0][m] = v.x; As[k4+1][m] = v.y; As[k4+2][m] = v.z; As[k4+3][m] = v.w;
    }
    #pragma unroll
    for (int i = 0; i < 4; i++){
      int flat = i*256 + tid;
      int k = flat >> 5, j4 = (flat & 31) << 2;
      float4 v = *(const float4*)(W + (size_t)(kb + k)*Ncols + col0 + j4);
      *(float4*)&Bs[k][j4] = v;
    }
    __syncthreads();
    #pragma unroll
    for (int k = 0; k < 32; k++){
      float4 b = *(const float4*)&Bs[k][tx << 2];
      float a[8];
      #pragma unroll
      for (int i = 0; i < 8; i++) a[i] = As[k][ty*8 + i];
      #pragma unroll
      for (int i = 0; i < 8; i++){
        acc[i][0] = fmaf(a[i], b.x, acc[i][0]);
        acc[i][1] = fmaf(a[i], b.y, acc[i][1]);
        acc[i][2] = fmaf(a[i], b.z, acc[i][2]);
        acc[i][3] = fmaf(a[i], b.w, acc[i][3]);
      }
    }
    __syncthreads();
  }

  float4 bi = *(const float4*)(bias + col0 + (tx << 2));
  #pragma unroll
  for (int i = 0; i < 8; i++){
    int gm = row0 + ty*8 + i;
    if (gm < M){
      float4 v;
      v.x = acc[i][0] + bi.x; v.y = acc[i][1] + bi.y;
      v.z = acc[i][2] + bi.z; v.w = acc[i][3] + bi.w;
      if (do_relu){
        v.x = fmaxf(v.x, 0.f); v.y = fmaxf(v.y, 0.f);
        v.z = fmaxf(v.z, 0.f); v.w = fmaxf(v.w, 0.f);
      }
      if (out_scale){ float s = out_scale[gm]; v.x*=s; v.y*=s; v.z*=s; v.w*=s; }
      *(float4*)(out + (size_t)gm*Ncols + col0 + (tx << 2)) = v;
    }
  }
}

// Avg-pool per graph: graph_ids sorted -> binary search bounds, wave per graph.
__global__ void pool_kernel(const float* __restrict__ h, const int* __restrict__ gid,
                            float* __restrict__ emb, int N, int G){
  int g = blockIdx.x;
  int lane = threadIdx.x;   // 64 threads
  int lo = 0, hi = N;
  while (lo < hi){ int mid = (lo + hi) >> 1; if (gid[mid] < g) lo = mid + 1; else hi = mid; }
  int start = lo;
  hi = N;
  while (lo < hi){ int mid = (lo + hi) >> 1; if (gid[mid] <= g) lo = mid + 1; else hi = mid; }
  int end = lo;
  float ax = 0.f, ay = 0.f;
  for (int n = start; n < end; n++){
    float2 v = ((const float2*)(h + (size_t)n*128))[lane];
    ax += v.x; ay += v.y;
  }
  int c = end - start; if (c < 1) c = 1;
  float invc = 1.0f / (float)c;
  float2 r; r.x = ax * invc; r.y = ay * invc;
  ((float2*)(emb + (size_t)g*128))[lane] = r;
}

// Final 256->1: wave per graph, float4 per lane, shuffle reduce.
__global__ void final_dot_kernel(const float* __restrict__ x, const float* __restrict__ w,
                                 const float* __restrict__ b, float* __restrict__ out, int G){
  int idx = blockIdx.x*blockDim.x + threadIdx.x;
  int g = idx >> 6, lane = idx & 63;
  if (g >= G) return;
  float4 xv = ((const float4*)(x + (size_t)g*256))[lane];
  float4 wv = ((const float4*)w)[lane];
  float s = xv.x*wv.x + xv.y*wv.y + xv.z*wv.z + xv.w*wv.w;
  for (int off = 32; off > 0; off >>= 1) s += __shfl_down(s, off);
  if (lane == 0) out[g] = s + b[0];
}

extern "C" void kernel_launch(void* const* d_in, const int* in_sizes, int n_in,
                              void* d_out, int out_size, void* d_ws, size_t ws_size,
                              hipStream_t stream){
  const float* feats = (const float*)d_in[0];
  const int*   src   = (const int*)d_in[1];
  const int*   dst   = (const int*)d_in[2];
  const int*   gid   = (const int*)d_in[3];
  const float* W0 = (const float*)d_in[4];   const float* b0 = (const float*)d_in[5];
  const float* W1 = (const float*)d_in[6];   const float* b1 = (const float*)d_in[7];
  const float* W2 = (const float*)d_in[8];   const float* b2 = (const float*)d_in[9];
  const float* Wm0 = (const float*)d_in[10]; const float* bm0 = (const float*)d_in[11];
  const float* Wm1 = (const float*)d_in[12]; const float* bm1 = (const float*)d_in[13];
  const float* Wm2 = (const float*)d_in[14]; const float* bm2 = (const float*)d_in[15];
  float* out = (float*)d_out;

  const int E   = in_sizes[1];
  const int N   = in_sizes[3];
  const int G   = out_size;
  const int MH  = in_sizes[11];   // 512
  const int MH2 = in_sizes[13];   // 256
  const int NB  = ceil_div(N, 128);   // 782 for N=100000 (<= NBMAX)

  char* ws = (char*)d_ws;
  size_t off = 0;
  auto carve = [&](size_t bytes) -> char* {
    off = (off + 255) & ~(size_t)255;
    char* p = ws + off; off += bytes; return p;
  };
  float* inv_src = (float*)carve((size_t)N*4);
  float* inv_dst = (float*)carve((size_t)N*4);
  int* row_ptr = (int*)carve((size_t)(N+1)*4);
  int* col     = (int*)carve((size_t)E*4);
  float* hs  = (float*)carve((size_t)N*128*4);
  float* agg = (float*)carve((size_t)N*128*4);
  float* emb = (float*)carve((size_t)G*128*4);
  float* x1  = (float*)carve((size_t)G*MH*4);
  float* x2  = (float*)carve((size_t)G*MH2*4);

  // CSR-build temporaries alias agg (dead until first csr_agg).
  // u32 layout: cntA[B1*NB] | cntB[B1*NB] | totals[2*NB] | baseA[NB+1] | baseB[NB+1]
  //             | bsrc_d[E] | bdst_d[E] | bsrc_s[E]
  unsigned* T = (unsigned*)agg;
  unsigned* cntA   = T;
  unsigned* cntB   = cntA + (size_t)B1*NB;
  unsigned* totals = cntB + (size_t)B1*NB;
  unsigned* baseA  = totals + 2*(size_t)NB;
  unsigned* baseB  = baseA + (NB+1);
  int* bsrc_d = (int*)(baseB + (NB+1));
  int* bdst_d = bsrc_d + E;
  int* bsrc_s = bdst_d + E;

  bucket_count_kernel<<<B1, 256, 0, stream>>>(src, dst, cntA, cntB, E, NB);
  scan_cols_kernel<<<dim3(ceil_div(NB,256), 2), 256, 0, stream>>>(cntA, cntB, totals, NB);
  scan_base_kernel<<<1, NBMAX, 0, stream>>>(totals, baseA, baseB, NB, E);
  bucket_scatter_kernel<<<B1, 256, 0, stream>>>(src, dst, cntA, cntB, baseA, baseB,
                                                bsrc_d, bdst_d, bsrc_s, E, NB);
  csr_finalize_kernel<<<NB, 256, 0, stream>>>(bsrc_d, bdst_d, baseA, row_ptr, inv_dst, col, N, E, NB);
  degout_finalize_kernel<<<NB, 256, 0, stream>>>(bsrc_s, baseB, inv_src, N);
  scale_rows_kernel<<<ceil_div(N*32,256), 256, 0, stream>>>(feats, inv_src, hs, N*32);

  const int agg_blocks = ceil_div(N*64, 256);
  dim3 ggrid(ceil_div(N,64), 1);
  // layer 0: agg = CSR-sum(hs); hs = relu(agg*inv_dst @ W0 + b0) * inv_src
  csr_agg_kernel<<<agg_blocks, 256, 0, stream>>>(row_ptr, col, hs, agg, N);
  gemm_kernel<<<ggrid, 256, 0, stream>>>(agg, W0, b0, inv_dst, inv_src, hs, N, 128, 128, 1);
  // layer 1
  csr_agg_kernel<<<agg_blocks, 256, 0, stream>>>(row_ptr, col, hs, agg, N);
  gemm_kernel<<<ggrid, 256, 0, stream>>>(agg, W1, b1, inv_dst, inv_src, hs, N, 128, 128, 1);
  // layer 2 (no out_scale: plain h3 for pooling)
  csr_agg_kernel<<<agg_blocks, 256, 0, stream>>>(row_ptr, col, hs, agg, N);
  gemm_kernel<<<ggrid, 256, 0, stream>>>(agg, W2, b2, inv_dst, nullptr, hs, N, 128, 128, 1);
  // avg pooling
  pool_kernel<<<G, 64, 0, stream>>>(hs, gid, emb, N, G);
  // MLP head
  gemm_kernel<<<dim3(ceil_div(G,64), MH/128),  256, 0, stream>>>(emb, Wm0, bm0, nullptr, nullptr, x1, G, 128, MH, 1);
  gemm_kernel<<<dim3(ceil_div(G,64), MH2/128), 256, 0, stream>>>(x1, Wm1, bm1, nullptr, nullptr, x2, G, MH, MH2, 1);
  final_dot_kernel<<<ceil_div(G*64,256), 256, 0, stream>>>(x2, Wm2, bm2, out, G);
}